// Round 1
// baseline (366.893 us; speedup 1.0000x reference)
//
#include <hip/hip_runtime.h>

#define NN 50000
#define EE 600000
#define DD 128

// ---------------- CSR build ----------------

__global__ void k_hist(const int* __restrict__ ei, int* __restrict__ deg) {
    int e = blockIdx.x * blockDim.x + threadIdx.x;
    if (e < EE) atomicAdd(&deg[ei[EE + e]], 1);
}

__global__ __launch_bounds__(1024) void k_scan(const int* __restrict__ deg,
                                               int* __restrict__ offs,
                                               int* __restrict__ cursor) {
    __shared__ int wsum[16];
    int t = threadIdx.x;
    int lane = t & 63, wid = t >> 6;
    int carry = 0;
    for (int base = 0; base < NN; base += 1024) {
        int i = base + t;
        int v = (i < NN) ? deg[i] : 0;
        // inclusive wave scan
        int s = v;
        #pragma unroll
        for (int d = 1; d < 64; d <<= 1) {
            int y = __shfl_up(s, d, 64);
            if (lane >= d) s += y;
        }
        if (lane == 63) wsum[wid] = s;
        __syncthreads();
        int wbase = 0, total = 0;
        #pragma unroll
        for (int w = 0; w < 16; ++w) {
            int ws = wsum[w];
            total += ws;
            if (w < wid) wbase += ws;
        }
        int incl = wbase + s;
        if (i < NN) {
            int ex = carry + incl - v;
            offs[i] = ex;
            cursor[i] = ex;
        }
        carry += total;
        __syncthreads();
    }
    if (t == 0) offs[NN] = carry;
}

__global__ void k_scatter(const int* __restrict__ ei, int* __restrict__ cursor,
                          int* __restrict__ srcList) {
    int e = blockIdx.x * blockDim.x + threadIdx.x;
    if (e < EE) {
        int s = ei[e];
        int d = ei[EE + e];
        int pos = atomicAdd(&cursor[d], 1);
        srcList[pos] = s;
    }
}

// ---------------- aggregation: h0 = x + sum_{src->i} x[src] ----------------
// one wave per node; lane holds float2 (64*2 = 128 cols)

__global__ __launch_bounds__(256) void k_agg(const float* __restrict__ x,
                                             const int* __restrict__ offs,
                                             const int* __restrict__ srcList,
                                             float* __restrict__ h0) {
    int wave = (blockIdx.x * blockDim.x + threadIdx.x) >> 6;
    int lane = threadIdx.x & 63;
    if (wave >= NN) return;
    const float2* x2 = (const float2*)x;
    float2 acc = x2[wave * 64 + lane];
    int s0 = offs[wave];
    int s1 = offs[wave + 1];
    for (int e = s0; e < s1; ++e) {
        int s = __builtin_amdgcn_readfirstlane(srcList[e]);
        float2 v = x2[s * 64 + lane];
        acc.x += v.x;
        acc.y += v.y;
    }
    ((float2*)h0)[wave * 64 + lane] = acc;
}

// ---------------- fp32 GEMM: C[N,128] = act(A[N,128] @ W[128,128] + b) ----------------
// BM=64 rows/block, k-tiles of 64. LDS: W-tile 32KB + A-tile padded 17.4KB.
// Thread computes 4 rows x 8 cols.

__global__ __launch_bounds__(256) void k_gemm(const float* __restrict__ A,
                                              const float* __restrict__ W,
                                              const float* __restrict__ bias,
                                              float* __restrict__ C, int do_relu) {
    __shared__ float Ash[64 * 68];    // stride 68 words (pad 4) -> 2-way-max bank alias
    __shared__ float Wsh[64 * 128];   // [kk][c]
    int t = threadIdx.x;
    int row0 = blockIdx.x * 64;
    int ri = t >> 4, ci = t & 15;
    int r0 = ri * 4, c0 = ci * 8;

    float acc[4][8];
    #pragma unroll
    for (int a = 0; a < 4; ++a)
        #pragma unroll
        for (int j = 0; j < 8; ++j) acc[a][j] = 0.f;

    for (int kt = 0; kt < 2; ++kt) {
        // load W k-rows [kt*64, kt*64+64) x 128 cols: 2048 float4, 8/thread
        float4* Wsh4 = (float4*)Wsh;
        #pragma unroll
        for (int i = 0; i < 8; ++i) {
            int idx = i * 256 + t;           // 0..2047
            int kk = idx >> 5;               // 0..63
            int c4 = idx & 31;
            Wsh4[idx] = ((const float4*)W)[(kt * 64 + kk) * 32 + c4];
        }
        // load A rows [row0, row0+64) x k-cols [kt*64, +64): 1024 float4, 4/thread
        #pragma unroll
        for (int i = 0; i < 4; ++i) {
            int idx = i * 256 + t;           // 0..1023
            int r = idx >> 4;                // 0..63 (16 float4 per row-tile)
            int c4 = idx & 15;
            int gr = row0 + r;
            float4 v = make_float4(0.f, 0.f, 0.f, 0.f);
            if (gr < NN) v = ((const float4*)A)[gr * 32 + kt * 16 + c4];
            *((float4*)&Ash[r * 68 + c4 * 4]) = v;
        }
        __syncthreads();

        #pragma unroll 4
        for (int k2 = 0; k2 < 64; ++k2) {
            float av[4];
            #pragma unroll
            for (int a = 0; a < 4; ++a) av[a] = Ash[(r0 + a) * 68 + k2];
            float4 w0 = *((const float4*)&Wsh[k2 * 128 + c0]);
            float4 w1 = *((const float4*)&Wsh[k2 * 128 + c0 + 4]);
            float wv[8] = {w0.x, w0.y, w0.z, w0.w, w1.x, w1.y, w1.z, w1.w};
            #pragma unroll
            for (int a = 0; a < 4; ++a)
                #pragma unroll
                for (int j = 0; j < 8; ++j)
                    acc[a][j] = fmaf(av[a], wv[j], acc[a][j]);
        }
        __syncthreads();
    }

    float4 bv0 = *((const float4*)&bias[c0]);
    float4 bv1 = *((const float4*)&bias[c0 + 4]);
    #pragma unroll
    for (int a = 0; a < 4; ++a) {
        int gr = row0 + r0 + a;
        if (gr < NN) {
            float o[8];
            o[0] = acc[a][0] + bv0.x; o[1] = acc[a][1] + bv0.y;
            o[2] = acc[a][2] + bv0.z; o[3] = acc[a][3] + bv0.w;
            o[4] = acc[a][4] + bv1.x; o[5] = acc[a][5] + bv1.y;
            o[6] = acc[a][6] + bv1.z; o[7] = acc[a][7] + bv1.w;
            if (do_relu) {
                #pragma unroll
                for (int j = 0; j < 8; ++j) o[j] = fmaxf(o[j], 0.f);
            }
            float4 o0 = make_float4(o[0], o[1], o[2], o[3]);
            float4 o1 = make_float4(o[4], o[5], o[6], o[7]);
            *((float4*)&C[gr * 128 + c0]) = o0;
            *((float4*)&C[gr * 128 + c0 + 4]) = o1;
        }
    }
}

// ---------------- BatchNorm stats ----------------

__global__ __launch_bounds__(256) void k_bnstats(const float* __restrict__ h,
                                                 float* __restrict__ stats) {
    int c = threadIdx.x & (DD - 1);
    int half = threadIdx.x >> 7;
    float s = 0.f, sq = 0.f;
    for (int r = blockIdx.x * 2 + half; r < NN; r += gridDim.x * 2) {
        float v = h[r * DD + c];
        s += v;
        sq += v * v;
    }
    atomicAdd(&stats[c], s);
    atomicAdd(&stats[DD + c], sq);
}

__global__ void k_bnfin(const float* __restrict__ stats, const float* __restrict__ gamma,
                        const float* __restrict__ beta, float* __restrict__ ss) {
    int c = threadIdx.x;
    if (c < DD) {
        float mean = stats[c] * (1.0f / NN);
        float var = stats[DD + c] * (1.0f / NN) - mean * mean;
        var = fmaxf(var, 0.f);
        float sc = gamma[c] * rsqrtf(var + 1e-5f);
        ss[c] = sc;
        ss[DD + c] = beta[c] - mean * sc;
    }
}

// ---------------- epilogue: out = x + relu(h2*scale + shift), in place ----------------

__global__ __launch_bounds__(256) void k_final(const float* __restrict__ x,
                                               float* __restrict__ h,
                                               const float* __restrict__ ss) {
    int idx = blockIdx.x * blockDim.x + threadIdx.x;
    if (idx >= NN * DD / 4) return;
    int cq = idx & 31;
    float4 hv = ((const float4*)h)[idx];
    float4 xv = ((const float4*)x)[idx];
    float4 sc = ((const float4*)ss)[cq];
    float4 sh = ((const float4*)ss)[32 + cq];
    float4 o;
    o.x = xv.x + fmaxf(fmaf(hv.x, sc.x, sh.x), 0.f);
    o.y = xv.y + fmaxf(fmaf(hv.y, sc.y, sh.y), 0.f);
    o.z = xv.z + fmaxf(fmaf(hv.z, sc.z, sh.z), 0.f);
    o.w = xv.w + fmaxf(fmaf(hv.w, sc.w, sh.w), 0.f);
    ((float4*)h)[idx] = o;
}

extern "C" void kernel_launch(void* const* d_in, const int* in_sizes, int n_in,
                              void* d_out, int out_size, void* d_ws, size_t ws_size,
                              hipStream_t stream) {
    (void)in_sizes; (void)n_in; (void)out_size; (void)ws_size;
    const float* x     = (const float*)d_in[0];
    const int*   ei    = (const int*)d_in[1];
    const float* w1    = (const float*)d_in[2];
    const float* b1    = (const float*)d_in[3];
    const float* w2    = (const float*)d_in[4];
    const float* b2    = (const float*)d_in[5];
    const float* gamma = (const float*)d_in[6];
    const float* beta  = (const float*)d_in[7];
    float* out = (float*)d_out;

    char* wsb = (char*)d_ws;
    int*   deg     = (int*)(wsb);                        // 200 KB
    int*   offs    = (int*)(wsb + (1u << 18));           // 256 KB: N+1 ints
    int*   cursor  = (int*)(wsb + (2u << 18));           // 512 KB
    int*   srcList = (int*)(wsb + (3u << 18));           // 768 KB .. 3.2 MB
    float* h1      = (float*)(wsb + (4u << 20));         // 4 MB .. 29.6 MB
    float* stats   = (float*)(wsb + 30u * (1u << 20));   // 30 MB: 256 floats
    float* ss      = stats + 2 * DD;                     // 256 floats

    hipMemsetAsync(deg, 0, NN * sizeof(int), stream);
    hipMemsetAsync(stats, 0, 2 * DD * sizeof(float), stream);

    k_hist<<<(EE + 255) / 256, 256, 0, stream>>>(ei, deg);
    k_scan<<<1, 1024, 0, stream>>>(deg, offs, cursor);
    k_scatter<<<(EE + 255) / 256, 256, 0, stream>>>(ei, cursor, srcList);
    // h0 -> d_out
    k_agg<<<(NN * 64) / 256 + 1, 256, 0, stream>>>(x, offs, srcList, out);
    // h1 = relu(h0 @ w1 + b1)
    k_gemm<<<(NN + 63) / 64, 256, 0, stream>>>(out, w1, b1, h1, 1);
    // h2 = h1 @ w2 + b2 -> d_out (h0 consumed)
    k_gemm<<<(NN + 63) / 64, 256, 0, stream>>>(h1, w2, b2, out, 0);
    k_bnstats<<<256, 256, 0, stream>>>(out, stats);
    k_bnfin<<<1, 128, 0, stream>>>(stats, gamma, beta, ss);
    k_final<<<(NN * DD / 4 + 255) / 256, 256, 0, stream>>>(x, out, ss);
}

// Round 2
// 318.481 us; speedup vs baseline: 1.1520x; 1.1520x over previous
//
#include <hip/hip_runtime.h>

#define NN 50000
#define EE 600000
#define DD 128
#define MTILE 64
#define LDSTR 136   // bf16 elems per LDS row: 272 B = 17*16 B (16B-aligned, breaks pow2 banks)

typedef __attribute__((ext_vector_type(8))) short short8;
typedef __attribute__((ext_vector_type(4))) float f32x4;

static __device__ __forceinline__ unsigned short f2bf(float f) {
    unsigned int u = __float_as_uint(f);
    u += 0x7FFF + ((u >> 16) & 1);   // round-to-nearest-even
    return (unsigned short)(u >> 16);
}

// ---------------- CSR build ----------------

__global__ void k_hist(const int* __restrict__ ei, int* __restrict__ deg) {
    int e = blockIdx.x * blockDim.x + threadIdx.x;
    if (e < EE) atomicAdd(&deg[ei[EE + e]], 1);
}

__global__ __launch_bounds__(1024) void k_scan(const int* __restrict__ deg,
                                               int* __restrict__ offs,
                                               int* __restrict__ cursor) {
    __shared__ int wsum[16];
    int t = threadIdx.x;
    int lane = t & 63, wid = t >> 6;
    int carry = 0;
    for (int base = 0; base < NN; base += 1024) {
        int i = base + t;
        int v = (i < NN) ? deg[i] : 0;
        int s = v;
        #pragma unroll
        for (int d = 1; d < 64; d <<= 1) {
            int y = __shfl_up(s, d, 64);
            if (lane >= d) s += y;
        }
        if (lane == 63) wsum[wid] = s;
        __syncthreads();
        int wbase = 0, total = 0;
        #pragma unroll
        for (int w = 0; w < 16; ++w) {
            int ws = wsum[w];
            total += ws;
            if (w < wid) wbase += ws;
        }
        int incl = wbase + s;
        if (i < NN) {
            int ex = carry + incl - v;
            offs[i] = ex;
            cursor[i] = ex;
        }
        carry += total;
        __syncthreads();
    }
    if (t == 0) offs[NN] = carry;
}

__global__ void k_scatter(const int* __restrict__ ei, int* __restrict__ cursor,
                          int* __restrict__ srcList) {
    int e = blockIdx.x * blockDim.x + threadIdx.x;
    if (e < EE) {
        int s = ei[e];
        int d = ei[EE + e];
        int pos = atomicAdd(&cursor[d], 1);
        srcList[pos] = s;
    }
}

// ---------------- weight prep: wt[w][n][k] = bf16(w[k][n]) ----------------

__global__ void k_prepw(const float* __restrict__ w1, const float* __restrict__ w2,
                        unsigned short* __restrict__ wt) {
    int tid = blockIdx.x * 256 + threadIdx.x;   // 0..32767
    int w = tid >> 14, idx = tid & 16383;
    int k = idx >> 7, n = idx & 127;
    const float* src = w ? w2 : w1;
    wt[w * 16384 + n * 128 + k] = f2bf(src[k * 128 + n]);
}

// ---------------- aggregation: h0 = bf16(x + sum_{src->i} x[src]) ----------------
// one wave per node; batch-load 64 src indices coalesced, shfl-broadcast,
// 4 independent row-gathers in flight per iteration.

__global__ __launch_bounds__(256) void k_agg(const float* __restrict__ x,
                                             const int* __restrict__ offs,
                                             const int* __restrict__ srcList,
                                             unsigned short* __restrict__ h0) {
    int wave = (blockIdx.x * blockDim.x + threadIdx.x) >> 6;
    int lane = threadIdx.x & 63;
    if (wave >= NN) return;
    const float2* x2 = (const float2*)x;
    float2 acc = x2[wave * 64 + lane];
    int s0 = offs[wave], s1 = offs[wave + 1];
    for (int base = s0; base < s1; base += 64) {
        int sv = 0;
        if (base + lane < s1) sv = srcList[base + lane];
        int m = s1 - base; if (m > 64) m = 64;
        int j = 0;
        for (; j + 4 <= m; j += 4) {
            int a0 = __shfl(sv, j, 64);
            int a1 = __shfl(sv, j + 1, 64);
            int a2 = __shfl(sv, j + 2, 64);
            int a3 = __shfl(sv, j + 3, 64);
            float2 v0 = x2[a0 * 64 + lane];
            float2 v1 = x2[a1 * 64 + lane];
            float2 v2 = x2[a2 * 64 + lane];
            float2 v3 = x2[a3 * 64 + lane];
            acc.x += v0.x + v1.x + v2.x + v3.x;
            acc.y += v0.y + v1.y + v2.y + v3.y;
        }
        for (; j < m; ++j) {
            int s = __shfl(sv, j, 64);
            float2 v = x2[s * 64 + lane];
            acc.x += v.x; acc.y += v.y;
        }
    }
    unsigned int packed = (unsigned int)f2bf(acc.x) | ((unsigned int)f2bf(acc.y) << 16);
    ((unsigned int*)h0)[wave * 64 + lane] = packed;
}

// ---------------- bf16 MFMA GEMM: C[N,128] = act(A[N,128] @ W + b) ----------------
// W pre-transposed bf16 [n][k]. Block = 256 thr (4 waves), 64 rows.
// Wave w: rows [w*16, w*16+16) x 128 cols = 8 C-tiles of 16x16.

__global__ __launch_bounds__(256) void k_gemm(const unsigned short* __restrict__ A,
                                              const unsigned short* __restrict__ W,
                                              const float* __restrict__ bias,
                                              unsigned short* __restrict__ Cb,
                                              float* __restrict__ Cf,
                                              int relu_bf16) {
    __shared__ __align__(16) unsigned short As[MTILE * LDSTR];
    __shared__ __align__(16) unsigned short Ws[128 * LDSTR];
    int t = threadIdx.x;
    int row0 = blockIdx.x * MTILE;

    // stage W: 128 rows x 128 bf16 = 2048 chunks of 8 ushorts
    #pragma unroll
    for (int i = 0; i < 8; ++i) {
        int idx = i * 256 + t;
        int r = idx >> 4, c = idx & 15;
        *(short8*)&Ws[r * LDSTR + c * 8] = *(const short8*)&W[r * 128 + c * 8];
    }
    // stage A: 64 rows x 128 bf16 = 1024 chunks
    #pragma unroll
    for (int i = 0; i < 4; ++i) {
        int idx = i * 256 + t;
        int r = idx >> 4, c = idx & 15;
        int gr = row0 + r;
        short8 v = (short8)0;
        if (gr < NN) v = *(const short8*)&A[gr * 128 + c * 8];
        *(short8*)&As[r * LDSTR + c * 8] = v;
    }
    __syncthreads();

    int lane = t & 63, wid = t >> 6;
    int m = lane & 15, quad = lane >> 4;
    f32x4 acc[8];
    #pragma unroll
    for (int i = 0; i < 8; ++i) acc[i] = (f32x4)0.f;

    #pragma unroll
    for (int kc = 0; kc < 4; ++kc) {
        int ko = kc * 32 + quad * 8;
        short8 af = *(const short8*)&As[(wid * 16 + m) * LDSTR + ko];
        #pragma unroll
        for (int nt = 0; nt < 8; ++nt) {
            short8 bfr = *(const short8*)&Ws[(nt * 16 + m) * LDSTR + ko];
            acc[nt] = __builtin_amdgcn_mfma_f32_16x16x32_bf16(af, bfr, acc[nt], 0, 0, 0);
        }
    }

    #pragma unroll
    for (int nt = 0; nt < 8; ++nt) {
        int col = nt * 16 + m;
        float bv = bias[col];
        #pragma unroll
        for (int r = 0; r < 4; ++r) {
            int gr = row0 + wid * 16 + quad * 4 + r;
            if (gr < NN) {
                float v = acc[nt][r] + bv;
                if (relu_bf16) {
                    Cb[gr * 128 + col] = f2bf(fmaxf(v, 0.f));
                } else {
                    Cf[gr * 128 + col] = v;
                }
            }
        }
    }
}

// ---------------- BatchNorm stats ----------------

__global__ __launch_bounds__(256) void k_bnstats(const float* __restrict__ h,
                                                 float* __restrict__ stats) {
    int c = threadIdx.x & (DD - 1);
    int half = threadIdx.x >> 7;
    float s = 0.f, sq = 0.f;
    for (int r = blockIdx.x * 2 + half; r < NN; r += gridDim.x * 2) {
        float v = h[r * DD + c];
        s += v;
        sq += v * v;
    }
    atomicAdd(&stats[c], s);
    atomicAdd(&stats[DD + c], sq);
}

__global__ void k_bnfin(const float* __restrict__ stats, const float* __restrict__ gamma,
                        const float* __restrict__ beta, float* __restrict__ ss) {
    int c = threadIdx.x;
    if (c < DD) {
        float mean = stats[c] * (1.0f / NN);
        float var = stats[DD + c] * (1.0f / NN) - mean * mean;
        var = fmaxf(var, 0.f);
        float sc = gamma[c] * rsqrtf(var + 1e-5f);
        ss[c] = sc;
        ss[DD + c] = beta[c] - mean * sc;
    }
}

// ---------------- epilogue: out = x + relu(h2*scale + shift), in place ----------------

__global__ __launch_bounds__(256) void k_final(const float* __restrict__ x,
                                               float* __restrict__ h,
                                               const float* __restrict__ ss) {
    int idx = blockIdx.x * blockDim.x + threadIdx.x;
    if (idx >= NN * DD / 4) return;
    int cq = idx & 31;
    float4 hv = ((const float4*)h)[idx];
    float4 xv = ((const float4*)x)[idx];
    float4 sc = ((const float4*)ss)[cq];
    float4 sh = ((const float4*)ss)[32 + cq];
    float4 o;
    o.x = xv.x + fmaxf(fmaf(hv.x, sc.x, sh.x), 0.f);
    o.y = xv.y + fmaxf(fmaf(hv.y, sc.y, sh.y), 0.f);
    o.z = xv.z + fmaxf(fmaf(hv.z, sc.z, sh.z), 0.f);
    o.w = xv.w + fmaxf(fmaf(hv.w, sc.w, sh.w), 0.f);
    ((float4*)h)[idx] = o;
}

extern "C" void kernel_launch(void* const* d_in, const int* in_sizes, int n_in,
                              void* d_out, int out_size, void* d_ws, size_t ws_size,
                              hipStream_t stream) {
    (void)in_sizes; (void)n_in; (void)out_size; (void)ws_size;
    const float* x     = (const float*)d_in[0];
    const int*   ei    = (const int*)d_in[1];
    const float* w1    = (const float*)d_in[2];
    const float* b1    = (const float*)d_in[3];
    const float* w2    = (const float*)d_in[4];
    const float* b2    = (const float*)d_in[5];
    const float* gamma = (const float*)d_in[6];
    const float* beta  = (const float*)d_in[7];
    float* out = (float*)d_out;

    char* wsb = (char*)d_ws;
    int*   deg     = (int*)(wsb);                         // 200 KB
    int*   offs    = (int*)(wsb + 0x40000);               // N+1 ints
    int*   cursor  = (int*)(wsb + 0x80000);
    int*   srcList = (int*)(wsb + 0xC0000);               // 2.4 MB
    unsigned short* wt  = (unsigned short*)(wsb + 0x380000);  // 64 KB (w1t | w2t)
    unsigned short* h0b = (unsigned short*)(wsb + (4u << 20));   // 12.8 MB bf16
    unsigned short* h1b = (unsigned short*)(wsb + (17u << 20));  // 12.8 MB bf16
    float* stats   = (float*)(wsb + 30u * (1u << 20));    // 256 floats
    float* ss      = stats + 2 * DD;

    hipMemsetAsync(deg, 0, NN * sizeof(int), stream);
    hipMemsetAsync(stats, 0, 2 * DD * sizeof(float), stream);

    k_prepw<<<128, 256, 0, stream>>>(w1, w2, wt);
    k_hist<<<(EE + 255) / 256, 256, 0, stream>>>(ei, deg);
    k_scan<<<1, 1024, 0, stream>>>(deg, offs, cursor);
    k_scatter<<<(EE + 255) / 256, 256, 0, stream>>>(ei, cursor, srcList);
    // h0 (bf16) = x + agg
    k_agg<<<(NN * 64 + 255) / 256, 256, 0, stream>>>(x, offs, srcList, h0b);
    // h1 (bf16) = relu(h0 @ w1 + b1)
    k_gemm<<<(NN + MTILE - 1) / MTILE, 256, 0, stream>>>(h0b, wt, b1, h1b, nullptr, 1);
    // h2 (fp32, d_out) = h1 @ w2 + b2
    k_gemm<<<(NN + MTILE - 1) / MTILE, 256, 0, stream>>>(h1b, wt + 16384, b2, nullptr, out, 0);
    k_bnstats<<<256, 256, 0, stream>>>(out, stats);
    k_bnfin<<<1, 128, 0, stream>>>(stats, gamma, beta, ss);
    k_final<<<(NN * DD / 4 + 255) / 256, 256, 0, stream>>>(x, out, ss);
}